// Round 4
// baseline (2144.628 us; speedup 1.0000x reference)
//
#include <hip/hip_runtime.h>

typedef unsigned short u16;
typedef unsigned int   u32;

#define NODE_D   38
#define EDGE_D   13
#define D_OUT    128
#define NEG_SLOPE 0.2f
#define LN_EPS   1e-5f

__device__ __forceinline__ float bf2f(u16 v) { return __uint_as_float(((u32)v) << 16); }
__device__ __forceinline__ u16 f2bf(float f) {
    u32 u = __float_as_uint(f);
    u += 0x7fffu + ((u >> 16) & 1u);   // round-to-nearest-even
    return (u16)(u >> 16);
}

// ---------------- degree + loop-attr accumulation (f32 inputs) ----------------
__global__ void k_deg_loop(const int* __restrict__ src, const int* __restrict__ dst,
                           const float* __restrict__ eattr, int E,
                           int* __restrict__ deg, float* __restrict__ loop_sum) {
    int e = blockIdx.x * blockDim.x + threadIdx.x;
    if (e >= E) return;
    int d = dst[e];
    atomicAdd(deg + d, 1);
#pragma unroll
    for (int k = 0; k < EDGE_D; k++)
        atomicAdd(loop_sum + (size_t)d * EDGE_D + k, eattr[(size_t)e * EDGE_D + k]);
}

// ---------------- single-block exclusive scan ----------------
__global__ void k_scan(const int* __restrict__ deg, int N, int* __restrict__ csr_off) {
    __shared__ int buf[2][256];
    __shared__ int base_sh;
    int t = threadIdx.x;
    if (t == 0) base_sh = 0;
    __syncthreads();
    for (int chunk = 0; chunk < N; chunk += 256) {
        int idx = chunk + t;
        int v = (idx < N) ? deg[idx] : 0;
        int cur = 0;
        buf[0][t] = v;
        __syncthreads();
        for (int ofs = 1; ofs < 256; ofs <<= 1) {
            int nxt = 1 - cur;
            int val = buf[cur][t];
            if (t >= ofs) val += buf[cur][t - ofs];
            buf[nxt][t] = val;
            __syncthreads();
            cur = nxt;
        }
        int inc = buf[cur][t];
        int excl = inc - v;
        int b = base_sh;
        if (idx < N) csr_off[idx] = b + excl;
        __syncthreads();
        if (t == 0) base_sh = b + buf[cur][255];
        __syncthreads();
    }
    if (t == 0) csr_off[N] = base_sh;
}

// ---------------- CSR fill ----------------
__global__ void k_fill(const int* __restrict__ src, const int* __restrict__ dst, int E,
                       const int* __restrict__ csr_off, int* __restrict__ fill,
                       int* __restrict__ csr_src, int* __restrict__ csr_eid) {
    int e = blockIdx.x * blockDim.x + threadIdx.x;
    if (e >= E) return;
    int d = dst[e];
    int pos = csr_off[d] + atomicAdd(fill + d, 1);
    csr_src[pos] = src[e];
    csr_eid[pos] = e;
}

// ---------------- self-loop edge attrs: mean of incoming ----------------
__global__ void k_self(const float* __restrict__ loop_sum, const int* __restrict__ deg,
                       int N, float* __restrict__ ea_self) {
    int i = blockIdx.x * blockDim.x + threadIdx.x;
    if (i >= N * EDGE_D) return;
    int n = i / EDGE_D;
    float invd = 1.f / fmaxf((float)deg[n], 1.f);
    ea_self[i] = loop_sum[i] * invd;
}

// ---------------- dense transform out[n][c] = sum_k in[n][k]*W[k][c] + b[c] ----------------
// IN_BF16: input buffer is internal bf16 (u16), else float32. Output bf16.
template <int K, bool IN_BF16>
__global__ __launch_bounds__(128) void k_tf(
    const void* __restrict__ in_v, const float* __restrict__ W,
    const float* __restrict__ bias, u16* __restrict__ out, int N) {
    __shared__ u16 Wsh[K * D_OUT];
    __shared__ float xrow[K];
    int c = threadIdx.x;
    for (int i = c; i < K * D_OUT; i += 128) Wsh[i] = f2bf(W[i]);
    float b = bias[c];
    __syncthreads();
    for (int n = blockIdx.x; n < N; n += gridDim.x) {
        if (IN_BF16) {
            const u16* in = (const u16*)in_v;
            for (int k = c; k < K; k += 128) xrow[k] = bf2f(in[(size_t)n * K + k]);
        } else {
            const float* in = (const float*)in_v;
            for (int k = c; k < K; k += 128) xrow[k] = in[(size_t)n * K + k];
        }
        __syncthreads();
        float acc = b;
        for (int k = 0; k < K; k++) acc += xrow[k] * bf2f(Wsh[k * D_OUT + c]);
        out[(size_t)n * D_OUT + c] = f2bf(acc);
        __syncthreads();
    }
}

// ---------------- fused GATv2 block (two-pass softmax) ----------------
// One wave per node. Lane l owns channels (2l, 2l+1); head = l>>4.
// xl/xr/res/hout: internal bf16. We/att/ab/lng/lnb/eattr/ea_self: float32.
__global__ __launch_bounds__(256) void k_gat(
    const int* __restrict__ csr_off, const int* __restrict__ csr_src,
    const int* __restrict__ csr_eid, const float* __restrict__ eattr,
    const float* __restrict__ ea_self,
    const u16* __restrict__ xl, const u16* __restrict__ xr,
    const u16* __restrict__ res, const float* __restrict__ We,
    const float* __restrict__ att, const float* __restrict__ ab,
    const float* __restrict__ lng, const float* __restrict__ lnb,
    u16* __restrict__ hout, int N, int E) {
    int wid = threadIdx.x >> 6;
    int lane = threadIdx.x & 63;
    int n = blockIdx.x * 4 + wid;
    if (n >= N) return;

    float we0[EDGE_D], we1[EDGE_D];
#pragma unroll
    for (int k = 0; k < EDGE_D; k++) {
        we0[k] = We[k * D_OUT + 2 * lane];
        we1[k] = We[k * D_OUT + 2 * lane + 1];
    }
    float a0 = att[2 * lane], a1 = att[2 * lane + 1];
    u32 xrw = ((const u32*)xr)[(size_t)n * 64 + lane];
    float xr0 = bf2f((u16)(xrw & 0xffff)), xr1 = bf2f((u16)(xrw >> 16));

    int beg = csr_off[n], end = csr_off[n + 1];

    // ---- pass 1: max logit per head ----
    float m = -3.0e38f;
    for (int i = beg; i <= end; i++) {
        int s; const float* ap;
        if (i < end) { s = csr_src[i]; ap = eattr + (size_t)csr_eid[i] * EDGE_D; }
        else         { s = n;          ap = ea_self + (size_t)n * EDGE_D; }
        float e0 = 0.f, e1 = 0.f;
#pragma unroll
        for (int k = 0; k < EDGE_D; k++) {
            float av = ap[k];
            e0 += av * we0[k];
            e1 += av * we1[k];
        }
        u32 xw = ((const u32*)xl)[(size_t)s * 64 + lane];
        float xs0 = bf2f((u16)(xw & 0xffff)), xs1 = bf2f((u16)(xw >> 16));
        float z0 = xs0 + xr0 + e0, z1 = xs1 + xr1 + e1;
        z0 = (z0 > 0.f) ? z0 : z0 * NEG_SLOPE;
        z1 = (z1 > 0.f) ? z1 : z1 * NEG_SLOPE;
        float p = z0 * a0 + z1 * a1;
        p += __shfl_xor(p, 1, 64);
        p += __shfl_xor(p, 2, 64);
        p += __shfl_xor(p, 4, 64);
        p += __shfl_xor(p, 8, 64);
        m = fmaxf(m, p);
    }

    // ---- pass 2: weighted sum ----
    float ssum = 0.f, acc0 = 0.f, acc1 = 0.f;
    for (int i = beg; i <= end; i++) {
        int s; const float* ap;
        if (i < end) { s = csr_src[i]; ap = eattr + (size_t)csr_eid[i] * EDGE_D; }
        else         { s = n;          ap = ea_self + (size_t)n * EDGE_D; }
        float e0 = 0.f, e1 = 0.f;
#pragma unroll
        for (int k = 0; k < EDGE_D; k++) {
            float av = ap[k];
            e0 += av * we0[k];
            e1 += av * we1[k];
        }
        u32 xw = ((const u32*)xl)[(size_t)s * 64 + lane];
        float xs0 = bf2f((u16)(xw & 0xffff)), xs1 = bf2f((u16)(xw >> 16));
        float z0 = xs0 + xr0 + e0, z1 = xs1 + xr1 + e1;
        z0 = (z0 > 0.f) ? z0 : z0 * NEG_SLOPE;
        z1 = (z1 > 0.f) ? z1 : z1 * NEG_SLOPE;
        float p = z0 * a0 + z1 * a1;
        p += __shfl_xor(p, 1, 64);
        p += __shfl_xor(p, 2, 64);
        p += __shfl_xor(p, 4, 64);
        p += __shfl_xor(p, 8, 64);
        float wgt = expf(p - m);
        ssum += wgt;
        acc0 += wgt * xs0;
        acc1 += wgt * xs1;
    }

    float inv = 1.f / fmaxf(ssum, 1e-30f);
    float o0 = acc0 * inv + ab[2 * lane];
    float o1 = acc1 * inv + ab[2 * lane + 1];
    o0 = (o0 > 0.f) ? o0 : (expf(o0) - 1.f);   // ELU
    o1 = (o1 > 0.f) ? o1 : (expf(o1) - 1.f);
    u32 rw = ((const u32*)res)[(size_t)n * 64 + lane];
    o0 += bf2f((u16)(rw & 0xffff));
    o1 += bf2f((u16)(rw >> 16));
    // LayerNorm over 128 channels (full-wave butterfly)
    float sm = o0 + o1;
#pragma unroll
    for (int mk = 1; mk < 64; mk <<= 1) sm += __shfl_xor(sm, mk, 64);
    float mu = sm * (1.f / 128.f);
    float d0 = o0 - mu, d1 = o1 - mu;
    float vv = d0 * d0 + d1 * d1;
#pragma unroll
    for (int mk = 1; mk < 64; mk <<= 1) vv += __shfl_xor(vv, mk, 64);
    float rs = rsqrtf(vv * (1.f / 128.f) + LN_EPS);
    float h0 = d0 * rs * lng[2 * lane]     + lnb[2 * lane];
    float h1 = d1 * rs * lng[2 * lane + 1] + lnb[2 * lane + 1];
    ((u32*)hout)[(size_t)n * 64 + lane] = (u32)f2bf(h0) | ((u32)f2bf(h1) << 16);
}

// ---------------- global mean-pool (sum via atomics) ----------------
__global__ void k_pool(const u16* __restrict__ h2, const int* __restrict__ batch,
                       int N, float* __restrict__ pooled, float* __restrict__ cnt) {
    int i = blockIdx.x * blockDim.x + threadIdx.x;
    if (i >= N * 64) return;
    int n = i >> 6, cp = i & 63;
    int g = batch[n];
    u32 v = ((const u32*)h2)[i];
    atomicAdd(pooled + (size_t)g * 128 + cp * 2,     bf2f((u16)(v & 0xffff)));
    atomicAdd(pooled + (size_t)g * 128 + cp * 2 + 1, bf2f((u16)(v >> 16)));
    if (cp == 0) atomicAdd(cnt + g, 1.f);
}

// ---------------- readout MLP: one wave per graph; OUTPUT FLOAT32 ----------------
__global__ __launch_bounds__(64) void k_readout(
    const float* __restrict__ pooled, const float* __restrict__ cnt,
    const float* __restrict__ Wd1, const float* __restrict__ bd1,
    const float* __restrict__ Wd2, const float* __restrict__ bd2,
    float* __restrict__ out, int G) {
    int g = blockIdx.x;
    int j = threadIdx.x;
    float invc = 1.f / fmaxf(cnt[g], 1.f);
    float acc = bd1[j];
    for (int k = 0; k < D_OUT; k++)
        acc += pooled[(size_t)g * 128 + k] * invc * Wd1[k * 64 + j];
    acc = fmaxf(acc, 0.f);
    float v = acc * Wd2[j];
#pragma unroll
    for (int mk = 1; mk < 64; mk <<= 1) v += __shfl_xor(v, mk, 64);
    if (j == 0) out[g] = v + bd2[0];
}

extern "C" void kernel_launch(void* const* d_in, const int* in_sizes, int n_in,
                              void* d_out, int out_size, void* d_ws, size_t ws_size,
                              hipStream_t stream) {
    const float* x     = (const float*)d_in[0];
    const int*   eidx  = (const int*)d_in[1];
    const float* eattr = (const float*)d_in[2];
    const int*   batch = (const int*)d_in[3];
    const float* Wl1 = (const float*)d_in[4],  *bl1 = (const float*)d_in[5];
    const float* Wr1 = (const float*)d_in[6],  *br1 = (const float*)d_in[7];
    const float* We1 = (const float*)d_in[8],  *att1 = (const float*)d_in[9],  *ab1 = (const float*)d_in[10];
    const float* lng1 = (const float*)d_in[11], *lnb1 = (const float*)d_in[12];
    const float* Wres = (const float*)d_in[13], *bres = (const float*)d_in[14];
    const float* Wl2 = (const float*)d_in[15], *bl2 = (const float*)d_in[16];
    const float* Wr2 = (const float*)d_in[17], *br2 = (const float*)d_in[18];
    const float* We2 = (const float*)d_in[19], *att2 = (const float*)d_in[20], *ab2 = (const float*)d_in[21];
    const float* lng2 = (const float*)d_in[22], *lnb2 = (const float*)d_in[23];
    const float* Wd1 = (const float*)d_in[24], *bd1 = (const float*)d_in[25];
    const float* Wd2 = (const float*)d_in[26], *bd2 = (const float*)d_in[27];

    int N = in_sizes[0] / NODE_D;
    int E = in_sizes[1] / 2;
    int G = out_size;
    const int* src = eidx;
    const int* dst = eidx + E;

    char* w = (char*)d_ws;
    auto alloc = [&](size_t bytes) -> char* {
        char* p = w;
        w += (bytes + 255) & ~(size_t)255;
        return p;
    };
    int*   deg      = (int*)alloc((size_t)N * 4);
    float* loop_sum = (float*)alloc((size_t)N * EDGE_D * 4);
    int*   fill     = (int*)alloc((size_t)N * 4);
    int*   csr_off  = (int*)alloc((size_t)(N + 1) * 4);
    int*   csr_src  = (int*)alloc((size_t)E * 4);
    int*   csr_eid  = (int*)alloc((size_t)E * 4);
    float* ea_self  = (float*)alloc((size_t)N * EDGE_D * 4);
    u16*   xlb      = (u16*)alloc((size_t)N * D_OUT * 2);
    u16*   xrb      = (u16*)alloc((size_t)N * D_OUT * 2);
    u16*   resb     = (u16*)alloc((size_t)N * D_OUT * 2);  // res1, then h2 output
    u16*   hb       = (u16*)alloc((size_t)N * D_OUT * 2);
    float* pooled   = (float*)alloc((size_t)G * D_OUT * 4);
    float* cnt      = (float*)alloc((size_t)G * 4);

    hipMemsetAsync(deg, 0, (size_t)N * 4, stream);
    hipMemsetAsync(loop_sum, 0, (size_t)N * EDGE_D * 4, stream);
    hipMemsetAsync(fill, 0, (size_t)N * 4, stream);
    hipMemsetAsync(pooled, 0, (size_t)G * D_OUT * 4, stream);
    hipMemsetAsync(cnt, 0, (size_t)G * 4, stream);

    k_deg_loop<<<(E + 255) / 256, 256, 0, stream>>>(src, dst, eattr, E, deg, loop_sum);
    k_scan<<<1, 256, 0, stream>>>(deg, N, csr_off);
    k_fill<<<(E + 255) / 256, 256, 0, stream>>>(src, dst, E, csr_off, fill, csr_src, csr_eid);
    k_self<<<(N * EDGE_D + 255) / 256, 256, 0, stream>>>(loop_sum, deg, N, ea_self);

    int tgrid = 4096;
    k_tf<NODE_D, false><<<tgrid, 128, 0, stream>>>(x, Wl1, bl1, xlb, N);
    k_tf<NODE_D, false><<<tgrid, 128, 0, stream>>>(x, Wr1, br1, xrb, N);
    k_tf<NODE_D, false><<<tgrid, 128, 0, stream>>>(x, Wres, bres, resb, N);

    k_gat<<<(N + 3) / 4, 256, 0, stream>>>(csr_off, csr_src, csr_eid, eattr, ea_self,
                                           xlb, xrb, resb, We1, att1, ab1, lng1, lnb1, hb, N, E);

    k_tf<D_OUT, true><<<tgrid, 128, 0, stream>>>(hb, Wl2, bl2, xlb, N);
    k_tf<D_OUT, true><<<tgrid, 128, 0, stream>>>(hb, Wr2, br2, xrb, N);

    // h2 output goes into resb (res1 no longer needed)
    k_gat<<<(N + 3) / 4, 256, 0, stream>>>(csr_off, csr_src, csr_eid, eattr, ea_self,
                                           xlb, xrb, hb, We2, att2, ab2, lng2, lnb2, resb, N, E);

    k_pool<<<(N * 64 + 255) / 256, 256, 0, stream>>>(resb, batch, N, pooled, cnt);
    k_readout<<<G, 64, 0, stream>>>(pooled, cnt, Wd1, bd1, Wd2, bd2, (float*)d_out, G);
}

// Round 5
// 1548.713 us; speedup vs baseline: 1.3848x; 1.3848x over previous
//
#include <hip/hip_runtime.h>

typedef unsigned short u16;
typedef unsigned int   u32;

#define NODE_D   38
#define EDGE_D   13
#define D_OUT    128
#define NEG_SLOPE 0.2f
#define LN_EPS   1e-5f

__device__ __forceinline__ float bf2f(u16 v) { return __uint_as_float(((u32)v) << 16); }
__device__ __forceinline__ u16 f2bf(float f) {
    u32 u = __float_as_uint(f);
    u += 0x7fffu + ((u >> 16) & 1u);   // round-to-nearest-even
    return (u16)(u >> 16);
}

// ---------------- degree count (int atomics only) ----------------
__global__ void k_deg(const int* __restrict__ dst, int E, int* __restrict__ deg) {
    int e = blockIdx.x * blockDim.x + threadIdx.x;
    if (e >= E) return;
    atomicAdd(deg + dst[e], 1);
}

// ---------------- multi-block exclusive scan (chunk = 1024) ----------------
#define SCAN_CHUNK 1024
__global__ void k_scan1(const int* __restrict__ deg, int N, int* __restrict__ bsum) {
    __shared__ int sh[256];
    int base = blockIdx.x * SCAN_CHUNK;
    int t = threadIdx.x;
    int s = 0;
#pragma unroll
    for (int i = 0; i < 4; i++) { int idx = base + t * 4 + i; if (idx < N) s += deg[idx]; }
    sh[t] = s; __syncthreads();
    for (int ofs = 128; ofs > 0; ofs >>= 1) {
        if (t < ofs) sh[t] += sh[t + ofs];
        __syncthreads();
    }
    if (t == 0) bsum[blockIdx.x] = sh[0];
}
__global__ void k_scan2(const int* __restrict__ bsum, int nb, int* __restrict__ boff) {
    if (threadIdx.x == 0) {
        int run = 0;
        for (int i = 0; i < nb; i++) { boff[i] = run; run += bsum[i]; }
        boff[nb] = run;
    }
}
__global__ void k_scan3(const int* __restrict__ deg, int N, const int* __restrict__ boff,
                        int nb, int* __restrict__ csr_off) {
    __shared__ int wtot[4];
    int base = blockIdx.x * SCAN_CHUNK;
    int t = threadIdx.x;
    int lane = t & 63, w = t >> 6;
    int v[4]; int s = 0;
#pragma unroll
    for (int i = 0; i < 4; i++) { int idx = base + t * 4 + i; v[i] = (idx < N) ? deg[idx] : 0; s += v[i]; }
    int inc = s;
#pragma unroll
    for (int ofs = 1; ofs < 64; ofs <<= 1) {
        int x = __shfl_up(inc, ofs, 64);
        if (lane >= ofs) inc += x;
    }
    if (lane == 63) wtot[w] = inc;
    __syncthreads();
    int wofs = 0;
    for (int i = 0; i < w; i++) wofs += wtot[i];
    int run = boff[blockIdx.x] + wofs + (inc - s);
#pragma unroll
    for (int i = 0; i < 4; i++) {
        int idx = base + t * 4 + i;
        if (idx < N) csr_off[idx] = run;
        run += v[i];
    }
    if (blockIdx.x == 0 && t == 0) csr_off[N] = boff[nb];
}

// ---------------- CSR fill ----------------
__global__ void k_fill(const int* __restrict__ src, const int* __restrict__ dst, int E,
                       const int* __restrict__ csr_off, int* __restrict__ fill,
                       int* __restrict__ csr_src, int* __restrict__ csr_eid) {
    int e = blockIdx.x * blockDim.x + threadIdx.x;
    if (e >= E) return;
    int d = dst[e];
    int pos = csr_off[d] + atomicAdd(fill + d, 1);
    csr_src[pos] = src[e];
    csr_eid[pos] = e;
}

// ---------------- self-loop edge attrs: mean of incoming, via CSR (no atomics) ----------------
__global__ void k_self(const int* __restrict__ csr_off, const int* __restrict__ csr_eid,
                       const float* __restrict__ eattr, int N, float* __restrict__ ea_self) {
    int i = blockIdx.x * blockDim.x + threadIdx.x;
    if (i >= N * EDGE_D) return;
    int n = i / EDGE_D, k = i - n * EDGE_D;
    int beg = csr_off[n], end = csr_off[n + 1];
    float s = 0.f;
    for (int j = beg; j < end; j++)
        s += eattr[(size_t)csr_eid[j] * EDGE_D + k];
    ea_self[i] = s / fmaxf((float)(end - beg), 1.f);
}

// ---------------- dense transform out[n][c] = sum_k in[n][k]*W[k][c] + b[c] ----------------
// 256 threads, 4 nodes per iteration; thread (c = t&127, half = t>>7) does 2 nodes.
template <int K, bool IN_BF16>
__global__ __launch_bounds__(256) void k_tf(
    const void* __restrict__ in_v, const float* __restrict__ W,
    const float* __restrict__ bias, u16* __restrict__ out, int N) {
    __shared__ u16 Wsh[K * D_OUT];
    __shared__ float xsh[4][K];
    int t = threadIdx.x;
    for (int i = t; i < K * D_OUT; i += 256) Wsh[i] = f2bf(W[i]);
    int c = t & 127, half = t >> 7;
    float b = bias[c];
    __syncthreads();
    for (int g0 = blockIdx.x * 4; g0 < N; g0 += gridDim.x * 4) {
        for (int i = t; i < 4 * K; i += 256) {
            int nn = i / K, kk = i - nn * K;
            int n = g0 + nn;
            if (n < N) {
                if (IN_BF16) xsh[nn][kk] = bf2f(((const u16*)in_v)[(size_t)n * K + kk]);
                else         xsh[nn][kk] = ((const float*)in_v)[(size_t)n * K + kk];
            } else xsh[nn][kk] = 0.f;
        }
        __syncthreads();
        int n0 = half * 2, n1 = n0 + 1;
        float acc0 = b, acc1 = b;
#pragma unroll
        for (int k = 0; k < K; k++) {
            float wv = bf2f(Wsh[k * D_OUT + c]);
            acc0 += xsh[n0][k] * wv;
            acc1 += xsh[n1][k] * wv;
        }
        if (g0 + n0 < N) out[(size_t)(g0 + n0) * D_OUT + c] = f2bf(acc0);
        if (g0 + n1 < N) out[(size_t)(g0 + n1) * D_OUT + c] = f2bf(acc1);
        __syncthreads();
    }
}

// ---------------- fused GATv2 block (single-pass online softmax) ----------------
// One wave per node. Lane l owns channels (2l, 2l+1); head = l>>4.
__global__ __launch_bounds__(256) void k_gat(
    const int* __restrict__ csr_off, const int* __restrict__ csr_src,
    const int* __restrict__ csr_eid, const float* __restrict__ eattr,
    const float* __restrict__ ea_self,
    const u16* __restrict__ xl, const u16* __restrict__ xr,
    const u16* __restrict__ res, const float* __restrict__ We,
    const float* __restrict__ att, const float* __restrict__ ab,
    const float* __restrict__ lng, const float* __restrict__ lnb,
    u16* __restrict__ hout, int N, int E) {
    int wid = threadIdx.x >> 6;
    int lane = threadIdx.x & 63;
    int n = blockIdx.x * 4 + wid;
    if (n >= N) return;

    float we0[EDGE_D], we1[EDGE_D];
#pragma unroll
    for (int k = 0; k < EDGE_D; k++) {
        we0[k] = We[k * D_OUT + 2 * lane];
        we1[k] = We[k * D_OUT + 2 * lane + 1];
    }
    float a0 = att[2 * lane], a1 = att[2 * lane + 1];
    u32 xrw = ((const u32*)xr)[(size_t)n * 64 + lane];
    float xr0 = bf2f((u16)(xrw & 0xffff)), xr1 = bf2f((u16)(xrw >> 16));

    int beg = csr_off[n], end = csr_off[n + 1];
    float m = -1e30f, ssum = 0.f, acc0 = 0.f, acc1 = 0.f;
    for (int i = beg; i <= end; i++) {
        int s; const float* ap;
        if (i < end) { s = csr_src[i]; ap = eattr + (size_t)csr_eid[i] * EDGE_D; }
        else         { s = n;          ap = ea_self + (size_t)n * EDGE_D; }
        float e0 = 0.f, e1 = 0.f;
#pragma unroll
        for (int k = 0; k < EDGE_D; k++) {
            float av = ap[k];
            e0 += av * we0[k];
            e1 += av * we1[k];
        }
        u32 xw = ((const u32*)xl)[(size_t)s * 64 + lane];
        float xs0 = bf2f((u16)(xw & 0xffff)), xs1 = bf2f((u16)(xw >> 16));
        float z0 = xs0 + xr0 + e0, z1 = xs1 + xr1 + e1;
        z0 = (z0 > 0.f) ? z0 : z0 * NEG_SLOPE;
        z1 = (z1 > 0.f) ? z1 : z1 * NEG_SLOPE;
        float p = z0 * a0 + z1 * a1;
        p += __shfl_xor(p, 1, 64);
        p += __shfl_xor(p, 2, 64);
        p += __shfl_xor(p, 4, 64);
        p += __shfl_xor(p, 8, 64);
        // online softmax (per head; all 16 lanes of a head agree on p)
        float mn = fmaxf(m, p);
        float sc  = __expf(m - mn);
        float wgt = __expf(p - mn);
        ssum = ssum * sc + wgt;
        acc0 = acc0 * sc + wgt * xs0;
        acc1 = acc1 * sc + wgt * xs1;
        m = mn;
    }

    float inv = 1.f / ssum;
    float o0 = acc0 * inv + ab[2 * lane];
    float o1 = acc1 * inv + ab[2 * lane + 1];
    o0 = (o0 > 0.f) ? o0 : (__expf(o0) - 1.f);   // ELU
    o1 = (o1 > 0.f) ? o1 : (__expf(o1) - 1.f);
    u32 rw = ((const u32*)res)[(size_t)n * 64 + lane];
    o0 += bf2f((u16)(rw & 0xffff));
    o1 += bf2f((u16)(rw >> 16));
    // LayerNorm over 128 channels (full-wave butterfly)
    float sm = o0 + o1;
#pragma unroll
    for (int mk = 1; mk < 64; mk <<= 1) sm += __shfl_xor(sm, mk, 64);
    float mu = sm * (1.f / 128.f);
    float d0 = o0 - mu, d1 = o1 - mu;
    float vv = d0 * d0 + d1 * d1;
#pragma unroll
    for (int mk = 1; mk < 64; mk <<= 1) vv += __shfl_xor(vv, mk, 64);
    float rs = rsqrtf(vv * (1.f / 128.f) + LN_EPS);
    float h0 = d0 * rs * lng[2 * lane]     + lnb[2 * lane];
    float h1 = d1 * rs * lng[2 * lane + 1] + lnb[2 * lane + 1];
    ((u32*)hout)[(size_t)n * 64 + lane] = (u32)f2bf(h0) | ((u32)f2bf(h1) << 16);
}

// ---------------- global mean-pool (sum via atomics) ----------------
__global__ void k_pool(const u16* __restrict__ h2, const int* __restrict__ batch,
                       int N, float* __restrict__ pooled, float* __restrict__ cnt) {
    int i = blockIdx.x * blockDim.x + threadIdx.x;
    if (i >= N * 64) return;
    int n = i >> 6, cp = i & 63;
    int g = batch[n];
    u32 v = ((const u32*)h2)[i];
    atomicAdd(pooled + (size_t)g * 128 + cp * 2,     bf2f((u16)(v & 0xffff)));
    atomicAdd(pooled + (size_t)g * 128 + cp * 2 + 1, bf2f((u16)(v >> 16)));
    if (cp == 0) atomicAdd(cnt + g, 1.f);
}

// ---------------- readout MLP: one wave per graph; OUTPUT FLOAT32 ----------------
__global__ __launch_bounds__(64) void k_readout(
    const float* __restrict__ pooled, const float* __restrict__ cnt,
    const float* __restrict__ Wd1, const float* __restrict__ bd1,
    const float* __restrict__ Wd2, const float* __restrict__ bd2,
    float* __restrict__ out, int G) {
    int g = blockIdx.x;
    int j = threadIdx.x;
    float invc = 1.f / fmaxf(cnt[g], 1.f);
    float acc = bd1[j];
    for (int k = 0; k < D_OUT; k++)
        acc += pooled[(size_t)g * 128 + k] * invc * Wd1[k * 64 + j];
    acc = fmaxf(acc, 0.f);
    float v = acc * Wd2[j];
#pragma unroll
    for (int mk = 1; mk < 64; mk <<= 1) v += __shfl_xor(v, mk, 64);
    if (j == 0) out[g] = v + bd2[0];
}

extern "C" void kernel_launch(void* const* d_in, const int* in_sizes, int n_in,
                              void* d_out, int out_size, void* d_ws, size_t ws_size,
                              hipStream_t stream) {
    const float* x     = (const float*)d_in[0];
    const int*   eidx  = (const int*)d_in[1];
    const float* eattr = (const float*)d_in[2];
    const int*   batch = (const int*)d_in[3];
    const float* Wl1 = (const float*)d_in[4],  *bl1 = (const float*)d_in[5];
    const float* Wr1 = (const float*)d_in[6],  *br1 = (const float*)d_in[7];
    const float* We1 = (const float*)d_in[8],  *att1 = (const float*)d_in[9],  *ab1 = (const float*)d_in[10];
    const float* lng1 = (const float*)d_in[11], *lnb1 = (const float*)d_in[12];
    const float* Wres = (const float*)d_in[13], *bres = (const float*)d_in[14];
    const float* Wl2 = (const float*)d_in[15], *bl2 = (const float*)d_in[16];
    const float* Wr2 = (const float*)d_in[17], *br2 = (const float*)d_in[18];
    const float* We2 = (const float*)d_in[19], *att2 = (const float*)d_in[20], *ab2 = (const float*)d_in[21];
    const float* lng2 = (const float*)d_in[22], *lnb2 = (const float*)d_in[23];
    const float* Wd1 = (const float*)d_in[24], *bd1 = (const float*)d_in[25];
    const float* Wd2 = (const float*)d_in[26], *bd2 = (const float*)d_in[27];

    int N = in_sizes[0] / NODE_D;
    int E = in_sizes[1] / 2;
    int G = out_size;
    const int* src = eidx;
    const int* dst = eidx + E;

    char* w = (char*)d_ws;
    auto alloc = [&](size_t bytes) -> char* {
        char* p = w;
        w += (bytes + 255) & ~(size_t)255;
        return p;
    };
    int NB = (N + SCAN_CHUNK - 1) / SCAN_CHUNK;
    int*   deg      = (int*)alloc((size_t)N * 4);
    int*   fill     = (int*)alloc((size_t)N * 4);
    int*   csr_off  = (int*)alloc((size_t)(N + 1) * 4);
    int*   bsum     = (int*)alloc((size_t)NB * 4);
    int*   boff     = (int*)alloc((size_t)(NB + 1) * 4);
    int*   csr_src  = (int*)alloc((size_t)E * 4);
    int*   csr_eid  = (int*)alloc((size_t)E * 4);
    float* ea_self  = (float*)alloc((size_t)N * EDGE_D * 4);
    u16*   xlb      = (u16*)alloc((size_t)N * D_OUT * 2);
    u16*   xrb      = (u16*)alloc((size_t)N * D_OUT * 2);
    u16*   resb     = (u16*)alloc((size_t)N * D_OUT * 2);  // res1, then h2 output
    u16*   hb       = (u16*)alloc((size_t)N * D_OUT * 2);
    float* pooled   = (float*)alloc((size_t)G * D_OUT * 4);
    float* cnt      = (float*)alloc((size_t)G * 4);

    hipMemsetAsync(deg, 0, (size_t)N * 4, stream);
    hipMemsetAsync(fill, 0, (size_t)N * 4, stream);
    hipMemsetAsync(pooled, 0, (size_t)G * D_OUT * 4, stream);
    hipMemsetAsync(cnt, 0, (size_t)G * 4, stream);

    k_deg<<<(E + 255) / 256, 256, 0, stream>>>(dst, E, deg);
    k_scan1<<<NB, 256, 0, stream>>>(deg, N, bsum);
    k_scan2<<<1, 64, 0, stream>>>(bsum, NB, boff);
    k_scan3<<<NB, 256, 0, stream>>>(deg, N, boff, NB, csr_off);
    k_fill<<<(E + 255) / 256, 256, 0, stream>>>(src, dst, E, csr_off, fill, csr_src, csr_eid);
    k_self<<<(N * EDGE_D + 255) / 256, 256, 0, stream>>>(csr_off, csr_eid, eattr, N, ea_self);

    int tgrid = 4096;
    k_tf<NODE_D, false><<<tgrid, 256, 0, stream>>>(x, Wl1, bl1, xlb, N);
    k_tf<NODE_D, false><<<tgrid, 256, 0, stream>>>(x, Wr1, br1, xrb, N);
    k_tf<NODE_D, false><<<tgrid, 256, 0, stream>>>(x, Wres, bres, resb, N);

    k_gat<<<(N + 3) / 4, 256, 0, stream>>>(csr_off, csr_src, csr_eid, eattr, ea_self,
                                           xlb, xrb, resb, We1, att1, ab1, lng1, lnb1, hb, N, E);

    k_tf<D_OUT, true><<<tgrid, 256, 0, stream>>>(hb, Wl2, bl2, xlb, N);
    k_tf<D_OUT, true><<<tgrid, 256, 0, stream>>>(hb, Wr2, br2, xrb, N);

    // h2 output goes into resb (res1 no longer needed)
    k_gat<<<(N + 3) / 4, 256, 0, stream>>>(csr_off, csr_src, csr_eid, eattr, ea_self,
                                           xlb, xrb, hb, We2, att2, ab2, lng2, lnb2, resb, N, E);

    k_pool<<<(N * 64 + 255) / 256, 256, 0, stream>>>(resb, batch, N, pooled, cnt);
    k_readout<<<G, 64, 0, stream>>>(pooled, cnt, Wd1, bd1, Wd2, bd2, (float*)d_out, G);
}

// Round 6
// 829.909 us; speedup vs baseline: 2.5842x; 1.8661x over previous
//
#include <hip/hip_runtime.h>

typedef unsigned short u16;
typedef unsigned int   u32;
typedef __attribute__((ext_vector_type(8))) short short8;
typedef __attribute__((ext_vector_type(4))) float float4v;

#define NODE_D   38
#define EDGE_D   13
#define D_OUT    128
#define NEG_SLOPE 0.2f
#define LN_EPS   1e-5f

__device__ __forceinline__ float bf2f(u16 v) { return __uint_as_float(((u32)v) << 16); }
__device__ __forceinline__ u16 f2bf(float f) {
    u32 u = __float_as_uint(f);
    u += 0x7fffu + ((u >> 16) & 1u);   // round-to-nearest-even
    return (u16)(u >> 16);
}

// ---------------- degree count ----------------
__global__ void k_deg(const int* __restrict__ dst, int E, int* __restrict__ deg) {
    int e = blockIdx.x * blockDim.x + threadIdx.x;
    if (e >= E) return;
    atomicAdd(deg + dst[e], 1);
}

// ---------------- multi-block exclusive scan (chunk = 1024) ----------------
#define SCAN_CHUNK 1024
__global__ void k_scan1(const int* __restrict__ deg, int N, int* __restrict__ bsum) {
    __shared__ int sh[256];
    int base = blockIdx.x * SCAN_CHUNK;
    int t = threadIdx.x;
    int s = 0;
#pragma unroll
    for (int i = 0; i < 4; i++) { int idx = base + t * 4 + i; if (idx < N) s += deg[idx]; }
    sh[t] = s; __syncthreads();
    for (int ofs = 128; ofs > 0; ofs >>= 1) {
        if (t < ofs) sh[t] += sh[t + ofs];
        __syncthreads();
    }
    if (t == 0) bsum[blockIdx.x] = sh[0];
}
__global__ void k_scan2(const int* __restrict__ bsum, int nb, int* __restrict__ boff) {
    if (threadIdx.x == 0) {
        int run = 0;
        for (int i = 0; i < nb; i++) { boff[i] = run; run += bsum[i]; }
        boff[nb] = run;
    }
}
__global__ void k_scan3(const int* __restrict__ deg, int N, const int* __restrict__ boff,
                        int nb, int* __restrict__ csr_off) {
    __shared__ int wtot[4];
    int base = blockIdx.x * SCAN_CHUNK;
    int t = threadIdx.x;
    int lane = t & 63, w = t >> 6;
    int v[4]; int s = 0;
#pragma unroll
    for (int i = 0; i < 4; i++) { int idx = base + t * 4 + i; v[i] = (idx < N) ? deg[idx] : 0; s += v[i]; }
    int inc = s;
#pragma unroll
    for (int ofs = 1; ofs < 64; ofs <<= 1) {
        int x = __shfl_up(inc, ofs, 64);
        if (lane >= ofs) inc += x;
    }
    if (lane == 63) wtot[w] = inc;
    __syncthreads();
    int wofs = 0;
    for (int i = 0; i < w; i++) wofs += wtot[i];
    int run = boff[blockIdx.x] + wofs + (inc - s);
#pragma unroll
    for (int i = 0; i < 4; i++) {
        int idx = base + t * 4 + i;
        if (idx < N) csr_off[idx] = run;
        run += v[i];
    }
    if (blockIdx.x == 0 && t == 0) csr_off[N] = boff[nb];
}

// ---------------- CSR fill ----------------
__global__ void k_fill(const int* __restrict__ src, const int* __restrict__ dst, int E,
                       const int* __restrict__ csr_off, int* __restrict__ fill,
                       int* __restrict__ csr_src, int* __restrict__ csr_eid) {
    int e = blockIdx.x * blockDim.x + threadIdx.x;
    if (e >= E) return;
    int d = dst[e];
    int pos = csr_off[d] + atomicAdd(fill + d, 1);
    csr_src[pos] = src[e];
    csr_eid[pos] = e;
}

// ---------------- self-loop edge attrs: mean of incoming, via CSR ----------------
__global__ void k_self(const int* __restrict__ csr_off, const int* __restrict__ csr_eid,
                       const float* __restrict__ eattr, int N, float* __restrict__ ea_self) {
    int i = blockIdx.x * blockDim.x + threadIdx.x;
    if (i >= N * EDGE_D) return;
    int n = i / EDGE_D, k = i - n * EDGE_D;
    int beg = csr_off[n], end = csr_off[n + 1];
    float s = 0.f;
    for (int j = beg; j < end; j++)
        s += eattr[(size_t)csr_eid[j] * EDGE_D + k];
    ea_self[i] = s / fmaxf((float)(end - beg), 1.f);
}

// ---------------- x: f32 [N x 38] -> bf16 [N x 64] zero-padded ----------------
__global__ void k_xpad(const float* __restrict__ x, int N, u16* __restrict__ xpad) {
    int i = blockIdx.x * blockDim.x + threadIdx.x;
    if (i >= N * 64) return;
    int n = i >> 6, k = i & 63;
    xpad[i] = f2bf(k < NODE_D ? x[(size_t)n * NODE_D + k] : 0.f);
}

// ---------------- MFMA multi-output transform ----------------
// in: bf16 [N x KPAD]. Computes [N x CT*16] = in @ [W0|W1|W2] (+bias), each W
// is f32 [KREAL x 128] (k >= KREAL zero-padded). Output col c -> outs[c>>7][n*128 + (c&127)].
// Layouts (verified, guide §3): A[m=lane&15][k=quad*8+j]; B staged transposed in LDS
// (Bsw[c][k], row stride KPAD+8 for bank-conflict freedom) -> one ds_read_b128/frag;
// C/D: col=lane&15, row=quad*4+reg.
template <int KPAD, int CT, int KREAL>
__global__ __launch_bounds__(256) void k_tf_mfma(
    const u16* __restrict__ in,
    const float* __restrict__ W0, const float* __restrict__ b0,
    const float* __restrict__ W1, const float* __restrict__ b1,
    const float* __restrict__ W2, const float* __restrict__ b2,
    u16* __restrict__ o0, u16* __restrict__ o1, u16* __restrict__ o2,
    int N) {
    constexpr int RS = KPAD + 8;
    __shared__ u16 Bsw[CT * 16 * RS];
    __shared__ float bsh[CT * 16];
    const float* Ws[3] = {W0, W1, W2};
    const float* bs[3] = {b0, b1, b2};
    u16* outs[3] = {o0, o1, o2};
    int t = threadIdx.x;
    for (int i = t; i < CT * 16 * KPAD; i += 256) {
        int c = i / KPAD, k = i - c * KPAD;
        float v = (k < KREAL) ? Ws[c >> 7][(size_t)k * 128 + (c & 127)] : 0.f;
        Bsw[c * RS + k] = f2bf(v);
    }
    for (int i = t; i < CT * 16; i += 256) bsh[i] = bs[i >> 7][i & 127];
    __syncthreads();

    int wid = t >> 6, lane = t & 63;
    int quad = lane >> 4, m = lane & 15;

    for (int g0 = blockIdx.x * 64; g0 < N; g0 += gridDim.x * 64) {
        int na = g0 + wid * 16 + m;
        if (na > N - 1) na = N - 1;
        short8 a[KPAD / 32];
#pragma unroll
        for (int kc = 0; kc < KPAD / 32; kc++)
            a[kc] = *(const short8*)(in + (size_t)na * KPAD + kc * 32 + quad * 8);
        float4v acc[CT];
#pragma unroll
        for (int ct = 0; ct < CT; ct++) acc[ct] = (float4v){0.f, 0.f, 0.f, 0.f};
#pragma unroll
        for (int ct = 0; ct < CT; ct++) {
#pragma unroll
            for (int kc = 0; kc < KPAD / 32; kc++) {
                short8 b = *(const short8*)(&Bsw[(ct * 16 + m) * RS + kc * 32 + quad * 8]);
                acc[ct] = __builtin_amdgcn_mfma_f32_16x16x32_bf16(a[kc], b, acc[ct], 0, 0, 0);
            }
        }
#pragma unroll
        for (int ct = 0; ct < CT; ct++) {
            int col = ct * 16 + m;
            u16* op = outs[col >> 7];
            int cc = col & 127;
            float bv = bsh[col];
#pragma unroll
            for (int r = 0; r < 4; r++) {
                int node = g0 + wid * 16 + quad * 4 + r;
                if (node < N) op[(size_t)node * 128 + cc] = f2bf(acc[ct][r] + bv);
            }
        }
    }
}

// ---------------- fused GATv2 block (single-pass online softmax) ----------------
// One wave per node. Lane l owns channels (2l, 2l+1); head = l>>4.
__global__ __launch_bounds__(256) void k_gat(
    const int* __restrict__ csr_off, const int* __restrict__ csr_src,
    const int* __restrict__ csr_eid, const float* __restrict__ eattr,
    const float* __restrict__ ea_self,
    const u16* __restrict__ xl, const u16* __restrict__ xr,
    const u16* __restrict__ res, const float* __restrict__ We,
    const float* __restrict__ att, const float* __restrict__ ab,
    const float* __restrict__ lng, const float* __restrict__ lnb,
    u16* __restrict__ hout, int N, int E) {
    int wid = threadIdx.x >> 6;
    int lane = threadIdx.x & 63;
    int n = blockIdx.x * 4 + wid;
    if (n >= N) return;

    float we0[EDGE_D], we1[EDGE_D];
#pragma unroll
    for (int k = 0; k < EDGE_D; k++) {
        we0[k] = We[k * D_OUT + 2 * lane];
        we1[k] = We[k * D_OUT + 2 * lane + 1];
    }
    float a0 = att[2 * lane], a1 = att[2 * lane + 1];
    u32 xrw = ((const u32*)xr)[(size_t)n * 64 + lane];
    float xr0 = bf2f((u16)(xrw & 0xffff)), xr1 = bf2f((u16)(xrw >> 16));

    int beg = csr_off[n], end = csr_off[n + 1];
    float m = -1e30f, ssum = 0.f, acc0 = 0.f, acc1 = 0.f;
    for (int i = beg; i <= end; i++) {
        int s; const float* ap;
        if (i < end) { s = csr_src[i]; ap = eattr + (size_t)csr_eid[i] * EDGE_D; }
        else         { s = n;          ap = ea_self + (size_t)n * EDGE_D; }
        float e0 = 0.f, e1 = 0.f;
#pragma unroll
        for (int k = 0; k < EDGE_D; k++) {
            float av = ap[k];
            e0 += av * we0[k];
            e1 += av * we1[k];
        }
        u32 xw = ((const u32*)xl)[(size_t)s * 64 + lane];
        float xs0 = bf2f((u16)(xw & 0xffff)), xs1 = bf2f((u16)(xw >> 16));
        float z0 = xs0 + xr0 + e0, z1 = xs1 + xr1 + e1;
        z0 = (z0 > 0.f) ? z0 : z0 * NEG_SLOPE;
        z1 = (z1 > 0.f) ? z1 : z1 * NEG_SLOPE;
        float p = z0 * a0 + z1 * a1;
        p += __shfl_xor(p, 1, 64);
        p += __shfl_xor(p, 2, 64);
        p += __shfl_xor(p, 4, 64);
        p += __shfl_xor(p, 8, 64);
        float mn = fmaxf(m, p);
        float sc  = __expf(m - mn);
        float wgt = __expf(p - mn);
        ssum = ssum * sc + wgt;
        acc0 = acc0 * sc + wgt * xs0;
        acc1 = acc1 * sc + wgt * xs1;
        m = mn;
    }

    float inv = 1.f / ssum;
    float o0 = acc0 * inv + ab[2 * lane];
    float o1 = acc1 * inv + ab[2 * lane + 1];
    o0 = (o0 > 0.f) ? o0 : (__expf(o0) - 1.f);   // ELU
    o1 = (o1 > 0.f) ? o1 : (__expf(o1) - 1.f);
    u32 rw = ((const u32*)res)[(size_t)n * 64 + lane];
    o0 += bf2f((u16)(rw & 0xffff));
    o1 += bf2f((u16)(rw >> 16));
    float sm = o0 + o1;
#pragma unroll
    for (int mk = 1; mk < 64; mk <<= 1) sm += __shfl_xor(sm, mk, 64);
    float mu = sm * (1.f / 128.f);
    float d0 = o0 - mu, d1 = o1 - mu;
    float vv = d0 * d0 + d1 * d1;
#pragma unroll
    for (int mk = 1; mk < 64; mk <<= 1) vv += __shfl_xor(vv, mk, 64);
    float rs = rsqrtf(vv * (1.f / 128.f) + LN_EPS);
    float h0 = d0 * rs * lng[2 * lane]     + lnb[2 * lane];
    float h1 = d1 * rs * lng[2 * lane + 1] + lnb[2 * lane + 1];
    ((u32*)hout)[(size_t)n * 64 + lane] = (u32)f2bf(h0) | ((u32)f2bf(h1) << 16);
}

// ---------------- global mean-pool (sum via atomics) ----------------
__global__ void k_pool(const u16* __restrict__ h2, const int* __restrict__ batch,
                       int N, float* __restrict__ pooled, float* __restrict__ cnt) {
    int i = blockIdx.x * blockDim.x + threadIdx.x;
    if (i >= N * 64) return;
    int n = i >> 6, cp = i & 63;
    int g = batch[n];
    u32 v = ((const u32*)h2)[i];
    atomicAdd(pooled + (size_t)g * 128 + cp * 2,     bf2f((u16)(v & 0xffff)));
    atomicAdd(pooled + (size_t)g * 128 + cp * 2 + 1, bf2f((u16)(v >> 16)));
    if (cp == 0) atomicAdd(cnt + g, 1.f);
}

// ---------------- readout MLP: one wave per graph; OUTPUT FLOAT32 ----------------
__global__ __launch_bounds__(64) void k_readout(
    const float* __restrict__ pooled, const float* __restrict__ cnt,
    const float* __restrict__ Wd1, const float* __restrict__ bd1,
    const float* __restrict__ Wd2, const float* __restrict__ bd2,
    float* __restrict__ out, int G) {
    int g = blockIdx.x;
    int j = threadIdx.x;
    float invc = 1.f / fmaxf(cnt[g], 1.f);
    float acc = bd1[j];
    for (int k = 0; k < D_OUT; k++)
        acc += pooled[(size_t)g * 128 + k] * invc * Wd1[k * 64 + j];
    acc = fmaxf(acc, 0.f);
    float v = acc * Wd2[j];
#pragma unroll
    for (int mk = 1; mk < 64; mk <<= 1) v += __shfl_xor(v, mk, 64);
    if (j == 0) out[g] = v + bd2[0];
}

extern "C" void kernel_launch(void* const* d_in, const int* in_sizes, int n_in,
                              void* d_out, int out_size, void* d_ws, size_t ws_size,
                              hipStream_t stream) {
    const float* x     = (const float*)d_in[0];
    const int*   eidx  = (const int*)d_in[1];
    const float* eattr = (const float*)d_in[2];
    const int*   batch = (const int*)d_in[3];
    const float* Wl1 = (const float*)d_in[4],  *bl1 = (const float*)d_in[5];
    const float* Wr1 = (const float*)d_in[6],  *br1 = (const float*)d_in[7];
    const float* We1 = (const float*)d_in[8],  *att1 = (const float*)d_in[9],  *ab1 = (const float*)d_in[10];
    const float* lng1 = (const float*)d_in[11], *lnb1 = (const float*)d_in[12];
    const float* Wres = (const float*)d_in[13], *bres = (const float*)d_in[14];
    const float* Wl2 = (const float*)d_in[15], *bl2 = (const float*)d_in[16];
    const float* Wr2 = (const float*)d_in[17], *br2 = (const float*)d_in[18];
    const float* We2 = (const float*)d_in[19], *att2 = (const float*)d_in[20], *ab2 = (const float*)d_in[21];
    const float* lng2 = (const float*)d_in[22], *lnb2 = (const float*)d_in[23];
    const float* Wd1 = (const float*)d_in[24], *bd1 = (const float*)d_in[25];
    const float* Wd2 = (const float*)d_in[26], *bd2 = (const float*)d_in[27];

    int N = in_sizes[0] / NODE_D;
    int E = in_sizes[1] / 2;
    int G = out_size;
    const int* src = eidx;
    const int* dst = eidx + E;

    char* w = (char*)d_ws;
    auto alloc = [&](size_t bytes) -> char* {
        char* p = w;
        w += (bytes + 255) & ~(size_t)255;
        return p;
    };
    int NB = (N + SCAN_CHUNK - 1) / SCAN_CHUNK;
    int*   deg      = (int*)alloc((size_t)N * 4);
    int*   fill     = (int*)alloc((size_t)N * 4);
    int*   csr_off  = (int*)alloc((size_t)(N + 1) * 4);
    int*   bsum     = (int*)alloc((size_t)NB * 4);
    int*   boff     = (int*)alloc((size_t)(NB + 1) * 4);
    int*   csr_src  = (int*)alloc((size_t)E * 4);
    int*   csr_eid  = (int*)alloc((size_t)E * 4);
    float* ea_self  = (float*)alloc((size_t)N * EDGE_D * 4);
    u16*   xpad     = (u16*)alloc((size_t)N * 64 * 2);
    u16*   xlb      = (u16*)alloc((size_t)N * D_OUT * 2);
    u16*   xrb      = (u16*)alloc((size_t)N * D_OUT * 2);
    u16*   resb     = (u16*)alloc((size_t)N * D_OUT * 2);  // res1, then h2 output
    u16*   hb       = (u16*)alloc((size_t)N * D_OUT * 2);
    float* pooled   = (float*)alloc((size_t)G * D_OUT * 4);
    float* cnt      = (float*)alloc((size_t)G * 4);

    hipMemsetAsync(deg, 0, (size_t)N * 4, stream);
    hipMemsetAsync(fill, 0, (size_t)N * 4, stream);
    hipMemsetAsync(pooled, 0, (size_t)G * D_OUT * 4, stream);
    hipMemsetAsync(cnt, 0, (size_t)G * 4, stream);

    k_deg<<<(E + 255) / 256, 256, 0, stream>>>(dst, E, deg);
    k_scan1<<<NB, 256, 0, stream>>>(deg, N, bsum);
    k_scan2<<<1, 64, 0, stream>>>(bsum, NB, boff);
    k_scan3<<<NB, 256, 0, stream>>>(deg, N, boff, NB, csr_off);
    k_fill<<<(E + 255) / 256, 256, 0, stream>>>(src, dst, E, csr_off, fill, csr_src, csr_eid);
    k_self<<<(N * EDGE_D + 255) / 256, 256, 0, stream>>>(csr_off, csr_eid, eattr, N, ea_self);
    k_xpad<<<(N * 64 + 255) / 256, 256, 0, stream>>>(x, N, xpad);

    // block-1 transforms fused: [N x 64] @ [64 x 384] -> xl1 | xr1 | res
    k_tf_mfma<64, 24, NODE_D><<<640, 256, 0, stream>>>(
        xpad, Wl1, bl1, Wr1, br1, Wres, bres, xlb, xrb, resb, N);

    k_gat<<<(N + 3) / 4, 256, 0, stream>>>(csr_off, csr_src, csr_eid, eattr, ea_self,
                                           xlb, xrb, resb, We1, att1, ab1, lng1, lnb1, hb, N, E);

    // block-2 transforms fused: [N x 128] @ [128 x 256] -> xl2 | xr2
    k_tf_mfma<128, 16, 128><<<640, 256, 0, stream>>>(
        hb, Wl2, bl2, Wr2, br2, Wr2, br2, xlb, xrb, xrb, N);

    // h2 output goes into resb (res1 no longer needed)
    k_gat<<<(N + 3) / 4, 256, 0, stream>>>(csr_off, csr_src, csr_eid, eattr, ea_self,
                                           xlb, xrb, hb, We2, att2, ab2, lng2, lnb2, resb, N, E);

    k_pool<<<(N * 64 + 255) / 256, 256, 0, stream>>>(resb, batch, N, pooled, cnt);
    k_readout<<<G, 64, 0, stream>>>(pooled, cnt, Wd1, bd1, Wd2, bd2, (float*)d_out, G);
}